// Round 1
// baseline (536.383 us; speedup 1.0000x reference)
//
#include <hip/hip_runtime.h>
#include <math.h>

#define NFEA  64
#define NHID  32
#define NHEAD 3
#define LCAP  512   // atoms whose logits/e fit in LDS; overflow path handles the rest

typedef float v2f __attribute__((ext_vector_type(2)));

// Per-atom MLP: logits = SiLU(x @ W1 + b1) @ W2 + b2
// x row is per-lane (vector loads); W1/b1/W2/b2 indices are wave-uniform ->
// compiler should emit s_load (scalar pipe). Inner product uses 2-wide vector
// fma to select v_pk_fma_f32.
__device__ __forceinline__ void mlp_logits(
    const float* __restrict__ xrow,
    const float* __restrict__ W1, const float* __restrict__ b1,
    const float* __restrict__ W2, const float* __restrict__ b2,
    float lg[NHEAD])
{
  float4 xr[16];
#pragma unroll
  for (int q = 0; q < 16; ++q) xr[q] = ((const float4*)xrow)[q];

  v2f h[16];
#pragma unroll
  for (int j = 0; j < 16; ++j) h[j] = ((const v2f*)b1)[j];

#pragma unroll
  for (int q = 0; q < 16; ++q) {
    float xs[4] = {xr[q].x, xr[q].y, xr[q].z, xr[q].w};
#pragma unroll
    for (int dd = 0; dd < 4; ++dd) {
      v2f xd2 = {xs[dd], xs[dd]};
      const v2f* wrow = ((const v2f*)W1) + (q * 4 + dd) * 16;
#pragma unroll
      for (int j = 0; j < 16; ++j)
        h[j] = __builtin_elementwise_fma(xd2, wrow[j], h[j]);
    }
  }

  float l0 = b2[0], l1 = b2[1], l2 = b2[2];
#pragma unroll
  for (int j = 0; j < 16; ++j) {
#pragma unroll
    for (int c = 0; c < 2; ++c) {
      float hj = h[j][c];
      // SiLU: x * sigmoid(x) = x * rcp(1 + e^-x); rcp is ~1ulp, fine vs 9.8e-3 threshold
      float s = hj * __builtin_amdgcn_rcpf(1.0f + __expf(-hj));
      int jj = 2 * j + c;
      l0 = fmaf(s, W2[jj * 3 + 0], l0);
      l1 = fmaf(s, W2[jj * 3 + 1], l1);
      l2 = fmaf(s, W2[jj * 3 + 2], l2);
    }
  }
  lg[0] = l0; lg[1] = l1; lg[2] = l2;
}

// Segment starts from sorted owner array: starts[g] = first atom with owner >= g.
// starts has n_graphs+1 entries; empty graphs and the tail handled by the gap loops.
__global__ void gar_starts(const int* __restrict__ owner, int* __restrict__ starts,
                           int n_atoms, int n_graphs)
{
  int a = blockIdx.x * blockDim.x + threadIdx.x;
  if (a >= n_atoms) return;
  int cur  = owner[a];
  int prev = (a == 0) ? -1 : owner[a - 1];
  for (int g = prev + 1; g <= cur; ++g) starts[g] = a;
  if (a == n_atoms - 1)
    for (int g = cur + 1; g <= n_graphs; ++g) starts[g] = n_atoms;
}

// One wave (64 threads) per graph. Phases:
//  P1: thread=atom MLP -> logits to LDS, running per-head max (wave reduce)
//  P2: e = exp(lg - m) in LDS, per-head denom partials
//  P3a: lane=feature pooling, coalesced 256B x-row reads (L1/L2-hot), e broadcast from LDS
//  P3b: overflow chunks (n > LCAP) recompute path — correctness only, cold
__global__ __launch_bounds__(64, 4) void gar_main(
    const float* __restrict__ atom_feas,
    const int*   __restrict__ starts,
    const float* __restrict__ W1, const float* __restrict__ b1,
    const float* __restrict__ W2, const float* __restrict__ b2,
    float* __restrict__ out)
{
  __shared__ float4 elds[LCAP];
  const int g = blockIdx.x;
  const int t = threadIdx.x;
  const int s0 = starts[g];
  const int s1 = starts[g + 1];
  const int n  = s1 - s0;
  float* __restrict__ outg = out + (size_t)g * (NFEA * NHEAD);

  if (n <= 0) {  // empty graph: reference segment_sum gives zeros
    outg[t * 3 + 0] = 0.f; outg[t * 3 + 1] = 0.f; outg[t * 3 + 2] = 0.f;
    return;
  }

  const int nc = (n + 63) >> 6;
  float m0 = -INFINITY, m1 = -INFINITY, m2 = -INFINITY;

  for (int c = 0; c < nc; ++c) {            // uniform trip count
    int i = (c << 6) + t;
    bool act = i < n;
    int aa = s0 + (act ? i : (n - 1));      // clamp keeps loads valid & CF uniform
    float lg[3];
    mlp_logits(atom_feas + (size_t)aa * NFEA, W1, b1, W2, b2, lg);
    if (act) {
      m0 = fmaxf(m0, lg[0]); m1 = fmaxf(m1, lg[1]); m2 = fmaxf(m2, lg[2]);
      if (i < LCAP) elds[i] = make_float4(lg[0], lg[1], lg[2], 0.f);
    }
  }
#pragma unroll
  for (int off = 32; off > 0; off >>= 1) {
    m0 = fmaxf(m0, __shfl_xor(m0, off));
    m1 = fmaxf(m1, __shfl_xor(m1, off));
    m2 = fmaxf(m2, __shfl_xor(m2, off));
  }
  __syncthreads();

  float d0 = 0.f, d1 = 0.f, d2 = 0.f;
  const int ncached = n < LCAP ? n : LCAP;
  for (int i = t; i < ncached; i += 64) {
    float4 v = elds[i];
    float e0 = __expf(v.x - m0);
    float e1 = __expf(v.y - m1);
    float e2 = __expf(v.z - m2);
    elds[i] = make_float4(e0, e1, e2, 0.f);
    d0 += e0; d1 += e1; d2 += e2;
  }
  __syncthreads();

  // P3a: lane t owns feature d=t. x read is 256B contiguous per wave per atom.
  float a0 = 0.f, a1 = 0.f, a2 = 0.f;
  const float* __restrict__ xcol = atom_feas + (size_t)s0 * NFEA + t;
#pragma unroll 4
  for (int a = 0; a < ncached; ++a) {
    float xv = xcol[(size_t)a * NFEA];
    float4 e = elds[a];                      // same-address broadcast: free
    a0 = fmaf(xv, e.x, a0);
    a1 = fmaf(xv, e.y, a1);
    a2 = fmaf(xv, e.z, a2);
  }

  // P3b: overflow (n > LCAP) — recompute e chunk-wise through the same LDS buffer.
  for (int c0 = LCAP; c0 < n; c0 += 64) {
    __syncthreads();                         // P3a/prev-chunk reads done before overwrite
    int i = c0 + t;
    bool act = i < n;
    int aa = s0 + (act ? i : (n - 1));
    float lg[3];
    mlp_logits(atom_feas + (size_t)aa * NFEA, W1, b1, W2, b2, lg);
    float e0 = act ? __expf(lg[0] - m0) : 0.f;
    float e1 = act ? __expf(lg[1] - m1) : 0.f;
    float e2 = act ? __expf(lg[2] - m2) : 0.f;
    d0 += e0; d1 += e1; d2 += e2;
    elds[t] = make_float4(e0, e1, e2, 0.f);
    __syncthreads();
    int cnt = n - c0; if (cnt > 64) cnt = 64;
    const float* xc2 = atom_feas + (size_t)(s0 + c0) * NFEA + t;
    for (int a = 0; a < cnt; ++a) {
      float xv = xc2[(size_t)a * NFEA];
      float4 e = elds[a];
      a0 = fmaf(xv, e.x, a0);
      a1 = fmaf(xv, e.y, a1);
      a2 = fmaf(xv, e.z, a2);
    }
  }

#pragma unroll
  for (int off = 32; off > 0; off >>= 1) {
    d0 += __shfl_xor(d0, off);
    d1 += __shfl_xor(d1, off);
    d2 += __shfl_xor(d2, off);
  }
  // n >= 1 -> max atom contributes e=1 -> denom >= 1, no div-by-zero
  float i0 = 1.f / d0, i1 = 1.f / d1, i2 = 1.f / d2;
  outg[t * 3 + 0] = a0 * i0;
  outg[t * 3 + 1] = a1 * i1;
  outg[t * 3 + 2] = a2 * i2;
}

extern "C" void kernel_launch(void* const* d_in, const int* in_sizes, int n_in,
                              void* d_out, int out_size, void* d_ws, size_t ws_size,
                              hipStream_t stream)
{
  const float* atom_feas = (const float*)d_in[0];
  const int*   owner     = (const int*)d_in[1];
  const float* W1        = (const float*)d_in[2];
  const float* b1        = (const float*)d_in[3];
  const float* W2        = (const float*)d_in[4];
  const float* b2        = (const float*)d_in[5];
  float* out = (float*)d_out;

  const int n_atoms  = in_sizes[1];
  const int n_graphs = out_size / (NFEA * NHEAD);

  int* starts = (int*)d_ws;  // n_graphs+1 ints

  hipLaunchKernelGGL(gar_starts, dim3((n_atoms + 255) / 256), dim3(256), 0, stream,
                     owner, starts, n_atoms, n_graphs);
  hipLaunchKernelGGL(gar_main, dim3(n_graphs), dim3(64), 0, stream,
                     atom_feas, starts, W1, b1, W2, b2, out);
}